// Round 1
// baseline (261.488 us; speedup 1.0000x reference)
//
#include <hip/hip_runtime.h>

// Problem constants (from reference): B=32, CIN=64, COUT=64, H=W=128, 1x1 conv
#define CIN   64
#define COUT  64
#define HW    16384          // 128*128
#define HW4   4096           // HW/4 (int4 units)
#define NPIX  (32 * HW)      // B * H * W = 524288

typedef int   v4i __attribute__((ext_vector_type(4)));

// ---------------------------------------------------------------------------
// Prep kernel: pack weights to int8 dwords + fold requant params.
// wp[o*16 + k] holds (w[o][4k..4k+3] - wzp[o]) as 4 signed bytes.
// params[o] = { scale_o, bias_o/os + ozp, as_float(sum_ci(w'-wzp)), 0 }
// ---------------------------------------------------------------------------
__global__ void prep_kernel(const int* __restrict__ w,
                            const float* __restrict__ wscale,
                            const int* __restrict__ wzp,
                            const float* __restrict__ bias,
                            const float* __restrict__ is_p,
                            const float* __restrict__ os_p,
                            const int* __restrict__ ozp_p,
                            int* __restrict__ wp,
                            float4* __restrict__ params) {
    int o = threadIdx.x;
    if (o >= COUT) return;
    int zp = wzp[o];
    int sum = 0;
    #pragma unroll
    for (int k = 0; k < 16; ++k) {
        int c0 = w[o * CIN + 4 * k + 0] - zp;
        int c1 = w[o * CIN + 4 * k + 1] - zp;
        int c2 = w[o * CIN + 4 * k + 2] - zp;
        int c3 = w[o * CIN + 4 * k + 3] - zp;
        sum += c0 + c1 + c2 + c3;
        wp[o * 16 + k] = (c0 & 0xff) | ((c1 & 0xff) << 8) |
                         ((c2 & 0xff) << 16) | ((c3 & 0xff) << 24);
    }
    float scale = is_p[0] * wscale[o] / os_p[0];
    float bterm = bias[o] / os_p[0] + (float)ozp_p[0];
    float4 pr;
    pr.x = scale;
    pr.y = bterm;
    pr.z = __int_as_float(sum);
    pr.w = 0.0f;
    params[o] = pr;
}

// ---------------------------------------------------------------------------
// Main kernel: 4 consecutive pixels / thread (512 blocks x 256 threads).
// All VMEM is dwordx4: 64 int4 loads (16B/lane x 64 lanes = 1KiB/instr) and
// 64 int4 nontemporal stores per thread. 4x fewer VMEM instructions and 4x
// the bytes-in-flight per wave vs the 1-px/thread version — attacks the
// latency-bound regime (VALUBusy 27% + HBM 30% + occupancy 35%).
// Weights broadcast from LDS (bank-conflict-free, SQ_LDS_BANK_CONFLICT=0).
// ---------------------------------------------------------------------------
__global__ __launch_bounds__(256) void conv_kernel(
    const int* __restrict__ x,
    const int* __restrict__ wp_g,
    const float4* __restrict__ params_g,
    const int* __restrict__ izp_p,
    int* __restrict__ out) {

    __shared__ int4   s_wp[COUT * 4];   // 64 outs x 16 dwords (as 4x int4) = 4 KB
    __shared__ float4 s_par[COUT];      // 1 KB

    int tid = threadIdx.x;
    // stage weights: 256 int4 = 1024 dwords, one per thread
    s_wp[tid] = ((const int4*)wp_g)[tid];
    if (tid < COUT) s_par[tid] = params_g[tid];
    int izp_adj = izp_p[0] - 128;       // 0 for the reference inputs; exact otherwise
    __syncthreads();

    int t = blockIdx.x * 256 + tid;     // quad index 0..131071
    int b = t >> 12;                    // / (HW/4): 4096 quads per image
    int q = t & (HW4 - 1);              // quad within image (pixel = 4*q)

    const v4i* xb = (const v4i*)(x + b * (CIN * HW)) + q;

    // px{j}[cg]: for pixel j of the quad, channel group cg (4 channels packed
    // as signed bytes (x-128) — byte XOR 0x80 trick on 0..255 values)
    int px0[16], px1[16], px2[16], px3[16];
    #pragma unroll
    for (int cg = 0; cg < 16; ++cg) {
        v4i v0 = xb[(4 * cg + 0) * HW4];   // channel 4cg+0, pixels 4q..4q+3
        v4i v1 = xb[(4 * cg + 1) * HW4];
        v4i v2 = xb[(4 * cg + 2) * HW4];
        v4i v3 = xb[(4 * cg + 3) * HW4];
        px0[cg] = (v0.x | (v1.x << 8) | (v2.x << 16) | (v3.x << 24)) ^ 0x80808080;
        px1[cg] = (v0.y | (v1.y << 8) | (v2.y << 16) | (v3.y << 24)) ^ 0x80808080;
        px2[cg] = (v0.z | (v1.z << 8) | (v2.z << 16) | (v3.z << 24)) ^ 0x80808080;
        px3[cg] = (v0.w | (v1.w << 8) | (v2.w << 16) | (v3.w << 24)) ^ 0x80808080;
    }

    v4i* ob = (v4i*)(out + b * (COUT * HW)) + q;

    // unroll 2 keeps register pressure moderate; ILP inside each o comes from
    // the 4 independent sdot4 chains (one per pixel)
    #pragma unroll 2
    for (int o = 0; o < COUT; ++o) {
        int wv[16];
        *(int4*)(&wv[0])  = s_wp[o * 4 + 0];
        *(int4*)(&wv[4])  = s_wp[o * 4 + 1];
        *(int4*)(&wv[8])  = s_wp[o * 4 + 2];
        *(int4*)(&wv[12]) = s_wp[o * 4 + 3];
        float4 pr = s_par[o];
        int wsum = __float_as_int(pr.z);
        int base = -izp_adj * wsum;      // izp correction (0 here)

        int a0 = base, a1 = base, a2 = base, a3 = base;
        #pragma unroll
        for (int cg = 0; cg < 16; ++cg) {
            a0 = __builtin_amdgcn_sdot4(px0[cg], wv[cg], a0, false);
            a1 = __builtin_amdgcn_sdot4(px1[cg], wv[cg], a1, false);
            a2 = __builtin_amdgcn_sdot4(px2[cg], wv[cg], a2, false);
            a3 = __builtin_amdgcn_sdot4(px3[cg], wv[cg], a3, false);
        }

        float f0 = fmaf((float)a0, pr.x, pr.y);
        float f1 = fmaf((float)a1, pr.x, pr.y);
        float f2 = fmaf((float)a2, pr.x, pr.y);
        float f3 = fmaf((float)a3, pr.x, pr.y);
        f0 = fminf(fmaxf(rintf(f0), 0.0f), 255.0f);   // v_rndne matches jnp.round
        f1 = fminf(fmaxf(rintf(f1), 0.0f), 255.0f);
        f2 = fminf(fmaxf(rintf(f2), 0.0f), 255.0f);
        f3 = fminf(fmaxf(rintf(f3), 0.0f), 255.0f);

        v4i r;
        r.x = (int)f0; r.y = (int)f1; r.z = (int)f2; r.w = (int)f3;
        __builtin_nontemporal_store(r, ob + o * HW4);  // write-once stream
    }
}

extern "C" void kernel_launch(void* const* d_in, const int* in_sizes, int n_in,
                              void* d_out, int out_size, void* d_ws, size_t ws_size,
                              hipStream_t stream) {
    const int*   x      = (const int*)d_in[0];     // [32,64,128,128] int32 (uint8 vals)
    const float* is_p   = (const float*)d_in[1];   // input_scale
    const int*   izp_p  = (const int*)d_in[2];     // input_zero_point
    const int*   w      = (const int*)d_in[3];     // [64,64,1,1] int32
    const float* wscale = (const float*)d_in[4];   // [64]
    const int*   wzp    = (const int*)d_in[5];     // [64]
    const float* bias   = (const float*)d_in[6];   // [64]
    const float* os_p   = (const float*)d_in[7];   // output_scale
    const int*   ozp_p  = (const int*)d_in[8];     // output_zero_point

    int* out = (int*)d_out;

    int*    wp     = (int*)d_ws;                       // 4096 B
    float4* params = (float4*)((char*)d_ws + 4096);    // 1024 B

    prep_kernel<<<1, 64, 0, stream>>>(w, wscale, wzp, bias, is_p, os_p, ozp_p, wp, params);

    // 524288 pixels / 4 per thread / 256 per block = 512 blocks
    conv_kernel<<<512, 256, 0, stream>>>(x, wp, params, izp_p, out);
}

// Round 2
// 261.328 us; speedup vs baseline: 1.0006x; 1.0006x over previous
//
#include <hip/hip_runtime.h>

// Problem constants (from reference): B=32, CIN=64, COUT=64, H=W=128, 1x1 conv
#define CIN   64
#define COUT  64
#define HW    16384          // 128*128
#define HW4   4096           // HW/4 (int4 units)
#define NPIX  (32 * HW)      // B * H * W = 524288

typedef int   v4i __attribute__((ext_vector_type(4)));

// ---------------------------------------------------------------------------
// Prep kernel: pack weights to int8 dwords + fold requant params.
// wp[o*16 + k] holds (w[o][4k..4k+3] - wzp[o]) as 4 signed bytes.
// params[o] = { scale_o, bias_o/os + ozp, as_float(sum_ci(w'-wzp)), 0 }
// ---------------------------------------------------------------------------
__global__ void prep_kernel(const int* __restrict__ w,
                            const float* __restrict__ wscale,
                            const int* __restrict__ wzp,
                            const float* __restrict__ bias,
                            const float* __restrict__ is_p,
                            const float* __restrict__ os_p,
                            const int* __restrict__ ozp_p,
                            int* __restrict__ wp,
                            float4* __restrict__ params) {
    int o = threadIdx.x;
    if (o >= COUT) return;
    int zp = wzp[o];
    int sum = 0;
    #pragma unroll
    for (int k = 0; k < 16; ++k) {
        int c0 = w[o * CIN + 4 * k + 0] - zp;
        int c1 = w[o * CIN + 4 * k + 1] - zp;
        int c2 = w[o * CIN + 4 * k + 2] - zp;
        int c3 = w[o * CIN + 4 * k + 3] - zp;
        sum += c0 + c1 + c2 + c3;
        wp[o * 16 + k] = (c0 & 0xff) | ((c1 & 0xff) << 8) |
                         ((c2 & 0xff) << 16) | ((c3 & 0xff) << 24);
    }
    float scale = is_p[0] * wscale[o] / os_p[0];
    float bterm = bias[o] / os_p[0] + (float)ozp_p[0];
    float4 pr;
    pr.x = scale;
    pr.y = bterm;
    pr.z = __int_as_float(sum);
    pr.w = 0.0f;
    params[o] = pr;
}

// ---------------------------------------------------------------------------
// Main kernel: 4 consecutive pixels / thread (512 blocks x 256 threads).
// All VMEM is dwordx4: 64 int4 loads (16B/lane x 64 lanes = 1KiB/instr) and
// 64 int4 nontemporal stores per thread.
//
// ROUND-1 POST-MORTEM FIX: __launch_bounds__(256, 2). Without the second
// arg the allocator targeted 8 waves/SIMD (<=64 VGPR), got VGPR_Count=44,
// and spilled the 64-dword px array to scratch (re-read every o-iter ->
// 95us, VALUBusy 21%). min-2-waves/EU permits up to 256 VGPRs so the
// packed pixels stay in registers; per-wave MLP (64 x 16B loads in
// flight) replaces TLP for latency hiding.
// ---------------------------------------------------------------------------
__global__ __launch_bounds__(256, 2) void conv_kernel(
    const int* __restrict__ x,
    const int* __restrict__ wp_g,
    const float4* __restrict__ params_g,
    const int* __restrict__ izp_p,
    int* __restrict__ out) {

    __shared__ int4   s_wp[COUT * 4];   // 64 outs x 16 dwords (as 4x int4) = 4 KB
    __shared__ float4 s_par[COUT];      // 1 KB

    int tid = threadIdx.x;
    // stage weights: 256 int4 = 1024 dwords, one per thread
    s_wp[tid] = ((const int4*)wp_g)[tid];
    if (tid < COUT) s_par[tid] = params_g[tid];
    int izp_adj = izp_p[0] - 128;       // 0 for the reference inputs; exact otherwise
    __syncthreads();

    int t = blockIdx.x * 256 + tid;     // quad index 0..131071
    int b = t >> 12;                    // / (HW/4): 4096 quads per image
    int q = t & (HW4 - 1);              // quad within image (pixel = 4*q)

    const v4i* xb = (const v4i*)(x + b * (CIN * HW)) + q;

    // px{j}[cg]: for pixel j of the quad, channel group cg (4 channels packed
    // as signed bytes (x-128) — byte XOR 0x80 trick on 0..255 values)
    int px0[16], px1[16], px2[16], px3[16];
    #pragma unroll
    for (int cg = 0; cg < 16; ++cg) {
        v4i v0 = xb[(4 * cg + 0) * HW4];   // channel 4cg+0, pixels 4q..4q+3
        v4i v1 = xb[(4 * cg + 1) * HW4];
        v4i v2 = xb[(4 * cg + 2) * HW4];
        v4i v3 = xb[(4 * cg + 3) * HW4];
        px0[cg] = (v0.x | (v1.x << 8) | (v2.x << 16) | (v3.x << 24)) ^ 0x80808080;
        px1[cg] = (v0.y | (v1.y << 8) | (v2.y << 16) | (v3.y << 24)) ^ 0x80808080;
        px2[cg] = (v0.z | (v1.z << 8) | (v2.z << 16) | (v3.z << 24)) ^ 0x80808080;
        px3[cg] = (v0.w | (v1.w << 8) | (v2.w << 16) | (v3.w << 24)) ^ 0x80808080;
    }

    v4i* ob = (v4i*)(out + b * (COUT * HW)) + q;

    // unroll 2: ILP inside each o comes from the 4 independent sdot4 chains
    #pragma unroll 2
    for (int o = 0; o < COUT; ++o) {
        int wv[16];
        *(int4*)(&wv[0])  = s_wp[o * 4 + 0];
        *(int4*)(&wv[4])  = s_wp[o * 4 + 1];
        *(int4*)(&wv[8])  = s_wp[o * 4 + 2];
        *(int4*)(&wv[12]) = s_wp[o * 4 + 3];
        float4 pr = s_par[o];
        int wsum = __float_as_int(pr.z);
        int base = -izp_adj * wsum;      // izp correction (0 here)

        int a0 = base, a1 = base, a2 = base, a3 = base;
        #pragma unroll
        for (int cg = 0; cg < 16; ++cg) {
            a0 = __builtin_amdgcn_sdot4(px0[cg], wv[cg], a0, false);
            a1 = __builtin_amdgcn_sdot4(px1[cg], wv[cg], a1, false);
            a2 = __builtin_amdgcn_sdot4(px2[cg], wv[cg], a2, false);
            a3 = __builtin_amdgcn_sdot4(px3[cg], wv[cg], a3, false);
        }

        float f0 = fmaf((float)a0, pr.x, pr.y);
        float f1 = fmaf((float)a1, pr.x, pr.y);
        float f2 = fmaf((float)a2, pr.x, pr.y);
        float f3 = fmaf((float)a3, pr.x, pr.y);
        f0 = fminf(fmaxf(rintf(f0), 0.0f), 255.0f);   // v_rndne matches jnp.round
        f1 = fminf(fmaxf(rintf(f1), 0.0f), 255.0f);
        f2 = fminf(fmaxf(rintf(f2), 0.0f), 255.0f);
        f3 = fminf(fmaxf(rintf(f3), 0.0f), 255.0f);

        v4i r;
        r.x = (int)f0; r.y = (int)f1; r.z = (int)f2; r.w = (int)f3;
        __builtin_nontemporal_store(r, ob + o * HW4);  // write-once stream
    }
}

extern "C" void kernel_launch(void* const* d_in, const int* in_sizes, int n_in,
                              void* d_out, int out_size, void* d_ws, size_t ws_size,
                              hipStream_t stream) {
    const int*   x      = (const int*)d_in[0];     // [32,64,128,128] int32 (uint8 vals)
    const float* is_p   = (const float*)d_in[1];   // input_scale
    const int*   izp_p  = (const int*)d_in[2];     // input_zero_point
    const int*   w      = (const int*)d_in[3];     // [64,64,1,1] int32
    const float* wscale = (const float*)d_in[4];   // [64]
    const int*   wzp    = (const int*)d_in[5];     // [64]
    const float* bias   = (const float*)d_in[6];   // [64]
    const float* os_p   = (const float*)d_in[7];   // output_scale
    const int*   ozp_p  = (const int*)d_in[8];     // output_zero_point

    int* out = (int*)d_out;

    int*    wp     = (int*)d_ws;                       // 4096 B
    float4* params = (float4*)((char*)d_ws + 4096);    // 1024 B

    prep_kernel<<<1, 64, 0, stream>>>(w, wscale, wzp, bias, is_p, os_p, ozp_p, wp, params);

    // 524288 pixels / 4 per thread / 256 per block = 512 blocks
    conv_kernel<<<512, 256, 0, stream>>>(x, wp, params, izp_p, out);
}